// Round 2
// baseline (11415.971 us; speedup 1.0000x reference)
//
#include <hip/hip_runtime.h>
#include <hip/hip_bf16.h>

#define BB 2
#define LL 4096
#define DD 1024
#define HH 4
#define DH 256
#define CH 32
#define NC (LL/CH)     // 128
#define BL (BB*LL)     // 8192
#define BLD ((size_t)BB*LL*DD) // 8388608

__device__ __forceinline__ float bf2f(unsigned short u) {
    union { float f; unsigned int i; } x; x.i = ((unsigned int)u) << 16; return x.f;
}
__device__ __forceinline__ unsigned short f2bf(float f) {
    union { float f; unsigned int i; } x; x.f = f;
    unsigned int r = x.i + 0x7FFFu + ((x.i >> 16) & 1u);
    return (unsigned short)(r >> 16);
}

// ---------------------------------------------------------------- GEMM (NT)
// C[M,N] = A[M,K] @ W[N,K]^T (+bias). 64x64 tile, 256 threads, 4x4 per thread.
__global__ __launch_bounds__(256) void gemm_nt(
    const float* __restrict__ A, int lda,
    const float* __restrict__ W, int ldw,
    const float* __restrict__ bias,
    float* __restrict__ C, int ldc,
    int M, int N, int K)
{
    __shared__ float As[16][68];
    __shared__ float Ws[16][68];
    const int t = threadIdx.x;
    const int tx = t & 15, ty = t >> 4;
    const int row0 = blockIdx.y * 64, col0 = blockIdx.x * 64;
    const int lr = t >> 2, lk = (t & 3) * 4;
    const float* Ap = A + (size_t)(row0 + lr) * lda + lk;
    const float* Wp = W + (size_t)(col0 + lr) * ldw + lk;
    float acc[4][4];
#pragma unroll
    for (int i = 0; i < 4; ++i)
#pragma unroll
        for (int j = 0; j < 4; ++j) acc[i][j] = 0.0f;

    for (int k0 = 0; k0 < K; k0 += 16) {
        float4 av = *(const float4*)(Ap + k0);
        float4 wv = *(const float4*)(Wp + k0);
        __syncthreads();
        As[lk+0][lr]=av.x; As[lk+1][lr]=av.y; As[lk+2][lr]=av.z; As[lk+3][lr]=av.w;
        Ws[lk+0][lr]=wv.x; Ws[lk+1][lr]=wv.y; Ws[lk+2][lr]=wv.z; Ws[lk+3][lr]=wv.w;
        __syncthreads();
#pragma unroll
        for (int kk = 0; kk < 16; ++kk) {
            float4 a = *(const float4*)&As[kk][ty*4];
            float4 b = *(const float4*)&Ws[kk][tx*4];
            acc[0][0] += a.x*b.x; acc[0][1] += a.x*b.y; acc[0][2] += a.x*b.z; acc[0][3] += a.x*b.w;
            acc[1][0] += a.y*b.x; acc[1][1] += a.y*b.y; acc[1][2] += a.y*b.z; acc[1][3] += a.y*b.w;
            acc[2][0] += a.z*b.x; acc[2][1] += a.z*b.y; acc[2][2] += a.z*b.z; acc[2][3] += a.z*b.w;
            acc[3][0] += a.w*b.x; acc[3][1] += a.w*b.y; acc[3][2] += a.w*b.z; acc[3][3] += a.w*b.w;
        }
    }
    const int orow = row0 + ty*4, ocol = col0 + tx*4;
    float4 bv = make_float4(0.f,0.f,0.f,0.f);
    if (bias) bv = *(const float4*)(bias + ocol);
#pragma unroll
    for (int i = 0; i < 4; ++i) {
        float4 o;
        o.x = acc[i][0] + bv.x; o.y = acc[i][1] + bv.y;
        o.z = acc[i][2] + bv.z; o.w = acc[i][3] + bv.w;
        *(float4*)(C + (size_t)(orow + i) * ldc + ocol) = o;
    }
}

// --------------------------------------- causal dwconv K=4 + silu + head-l2norm -> bf16
// one block per (b,l,h); thread d = channel within head
__global__ __launch_bounds__(256) void convnorm_qk_k(
    const float* __restrict__ x, const float* __restrict__ w,
    unsigned short* __restrict__ y)
{
    int bl = blockIdx.x >> 2;
    int h  = blockIdx.x & 3;
    int l  = bl & (LL - 1);
    int d  = threadIdx.x;
    int c  = h * DH + d;
    const float* wp = w + (size_t)c * 4;
    const float* xp = x + (size_t)bl * DD + c;
    float acc = wp[3] * xp[0];
    if (l >= 1) acc += wp[2] * xp[-(int)DD];
    if (l >= 2) acc += wp[1] * xp[-2*(int)DD];
    if (l >= 3) acc += wp[0] * xp[-3*(int)DD];
    acc = acc / (1.0f + expf(-acc));
    float s = acc * acc;
#pragma unroll
    for (int off = 32; off > 0; off >>= 1) s += __shfl_down(s, off);
    __shared__ float red[4];
    int wv = threadIdx.x >> 6, ln = threadIdx.x & 63;
    if (ln == 0) red[wv] = s;
    __syncthreads();
    float tot = red[0] + red[1] + red[2] + red[3];
    y[(size_t)bl * DD + c] = f2bf(acc * rsqrtf(tot));
}

// ------------------------------------------------- causal depthwise conv K=4 + silu (f32 out)
__global__ __launch_bounds__(256) void conv_silu_k(
    const float* __restrict__ x, const float* __restrict__ w, float* __restrict__ y)
{
    size_t idx = (size_t)blockIdx.x * 256 + threadIdx.x;   // over B*L*D
    int c = (int)(idx & (DD - 1));
    int bl = (int)(idx >> 10);
    int l = bl & (LL - 1);
    const float* wp = w + (size_t)c * 4;
    const float* xp = x + (size_t)bl * DD + c;
    float acc = wp[3] * xp[0];
    if (l >= 1) acc += wp[2] * xp[-(int)DD];
    if (l >= 2) acc += wp[1] * xp[-2*(int)DD];
    if (l >= 3) acc += wp[0] * xp[-3*(int)DD];
    y[idx] = acc / (1.0f + expf(-acc));
}

// ------------------------------------------------- FIR causal depthwise conv (no act)
template<int K>
__global__ __launch_bounds__(256) void fir_conv_k(
    const float* __restrict__ x, const float* __restrict__ filt, float* __restrict__ y)
{
    size_t idx = (size_t)blockIdx.x * 256 + threadIdx.x;
    int c = (int)(idx & (DD - 1));
    int bl = (int)(idx >> 10);
    int l = bl & (LL - 1);
    const float* fp = filt + (size_t)c * K;
    float acc = 0.0f;
#pragma unroll 8
    for (int tt = 0; tt < K; ++tt) {
        int ls = l - (K - 1) + tt;
        if (ls >= 0) acc += fp[tt] * x[idx + (size_t)(long)(ls - l) * DD];
    }
    y[idx] = acc;
}

// ------------------------------------------------- beta = sigmoid(hs @ b_proj^T)
__global__ __launch_bounds__(256) void beta_k(
    const float* __restrict__ hs, const float* __restrict__ bw, float* __restrict__ beta)
{
    int bl = blockIdx.x;
    const float* xr = hs + (size_t)bl * DD;
    float a0=0.f,a1=0.f,a2=0.f,a3=0.f;
    for (int k = threadIdx.x; k < DD; k += 256) {
        float xv = xr[k];
        a0 += xv * bw[k];
        a1 += xv * bw[DD + k];
        a2 += xv * bw[2*DD + k];
        a3 += xv * bw[3*DD + k];
    }
#pragma unroll
    for (int off = 32; off > 0; off >>= 1) {
        a0 += __shfl_down(a0, off); a1 += __shfl_down(a1, off);
        a2 += __shfl_down(a2, off); a3 += __shfl_down(a3, off);
    }
    __shared__ float red[4][4];
    int wv = threadIdx.x >> 6, ln = threadIdx.x & 63;
    if (ln == 0) { red[wv][0]=a0; red[wv][1]=a1; red[wv][2]=a2; red[wv][3]=a3; }
    __syncthreads();
    if (threadIdx.x < 4) {
        int h = threadIdx.x;
        float s = red[0][h] + red[1][h] + red[2][h] + red[3][h];
        beta[(size_t)bl * HH + h] = 1.0f / (1.0f + expf(-s));
    }
}

// ------------------------------------------------- per-chunk prep (bf16 q,k in; bf16 u,w out)
__global__ __launch_bounds__(256) void chunk_prep_k(
    const unsigned short* __restrict__ q, const unsigned short* __restrict__ k,
    const float* __restrict__ v, const float* __restrict__ beta,
    unsigned short* __restrict__ u_out, unsigned short* __restrict__ w_out,
    float* __restrict__ attn_out)
{
    int ci = blockIdx.x & (NC - 1);
    int bh = blockIdx.x >> 7;           // NC = 128
    int h = bh & (HH - 1), b = bh >> 2;
    __shared__ float kt[CH][DH + 4];
    __shared__ float Am[CH][CH + 1];
    __shared__ float Ab[CH][CH + 1];
    __shared__ float bet[CH];
    int t = threadIdx.x;
    size_t qgbase = (size_t)b * LL + (size_t)ci * CH;

    for (int i = t; i < CH * (DH / 4); i += 256) {
        int r = i >> 6;
        int c4 = (i & 63) * 4;
        ushort4 kv = *(const ushort4*)(k + (qgbase + r) * DD + h * DH + c4);
        kt[r][c4+0] = bf2f(kv.x); kt[r][c4+1] = bf2f(kv.y);
        kt[r][c4+2] = bf2f(kv.z); kt[r][c4+3] = bf2f(kv.w);
    }
    if (t < CH) bet[t] = beta[(qgbase + t) * HH + h];
    __syncthreads();

    // A init and attn
    int c = t >> 3, e0 = (t & 7) * 4;
    {
        float accA[4] = {0,0,0,0}, accT[4] = {0,0,0,0};
        const unsigned short* qrow = q + (qgbase + c) * DD + h * DH;
        for (int d0 = 0; d0 < DH; d0 += 4) {
            float4 kc = *(const float4*)&kt[c][d0];
            ushort4 qv = *(const ushort4*)(qrow + d0);
            float qx = bf2f(qv.x), qy = bf2f(qv.y), qz = bf2f(qv.z), qw = bf2f(qv.w);
#pragma unroll
            for (int e = 0; e < 4; ++e) {
                float4 ke = *(const float4*)&kt[e0 + e][d0];
                accA[e] += kc.x*ke.x + kc.y*ke.y + kc.z*ke.z + kc.w*ke.w;
                accT[e] += qx*ke.x + qy*ke.y + qz*ke.z + qw*ke.w;
            }
        }
        float bc = bet[c];
        size_t abase = (size_t)blockIdx.x * (CH * CH) + (size_t)c * CH;
#pragma unroll
        for (int e = 0; e < 4; ++e) {
            int ee = e0 + e;
            Am[c][ee] = (ee < c) ? (-bc * accA[e]) : 0.0f;
            attn_out[abase + ee] = (ee <= c) ? accT[e] : 0.0f;
        }
    }
    __syncthreads();

    // forward substitution (matches reference loop exactly)
    for (int i = 1; i < CH; ++i) {
        float upd = 0.0f;
        if (t < i) {
#pragma unroll
            for (int kk = 0; kk < CH; ++kk) upd += Am[i][kk] * Am[kk][t];
        }
        __syncthreads();
        if (t < i) Am[i][t] += upd;
        __syncthreads();
    }

    // Ab[c][e] = (Am + I)[c][e] * beta[e]
    for (int i = t; i < CH * CH; i += 256) {
        int cc = i >> 5, ee = i & 31;
        float val = Am[cc][ee] + (cc == ee ? 1.0f : 0.0f);
        Ab[cc][ee] = val * bet[ee];
    }
    __syncthreads();

    // u = Ab @ v ; w = Ab @ kt
    int c2 = t >> 3, dd0 = (t & 7) * 32;
    float accu[32];
#pragma unroll
    for (int j = 0; j < 32; ++j) accu[j] = 0.0f;
    for (int e = 0; e < CH; ++e) {
        float ab = Ab[c2][e];
        const float* vrow = v + (qgbase + e) * DD + h * DH + dd0;
#pragma unroll
        for (int j4 = 0; j4 < 8; ++j4) {
            float4 v4 = *(const float4*)(vrow + j4 * 4);
            accu[j4*4+0] += ab * v4.x; accu[j4*4+1] += ab * v4.y;
            accu[j4*4+2] += ab * v4.z; accu[j4*4+3] += ab * v4.w;
        }
    }
    size_t obase = ((size_t)bh * LL + (size_t)ci * CH + c2) * DH + dd0;
#pragma unroll
    for (int j4 = 0; j4 < 8; ++j4) {
        ushort4 o;
        o.x = f2bf(accu[j4*4+0]); o.y = f2bf(accu[j4*4+1]);
        o.z = f2bf(accu[j4*4+2]); o.w = f2bf(accu[j4*4+3]);
        *(ushort4*)(u_out + obase + j4*4) = o;
    }

#pragma unroll
    for (int j = 0; j < 32; ++j) accu[j] = 0.0f;
    for (int e = 0; e < CH; ++e) {
        float ab = Ab[c2][e];
#pragma unroll
        for (int j4 = 0; j4 < 8; ++j4) {
            float4 v4 = *(const float4*)&kt[e][dd0 + j4*4];
            accu[j4*4+0] += ab * v4.x; accu[j4*4+1] += ab * v4.y;
            accu[j4*4+2] += ab * v4.z; accu[j4*4+3] += ab * v4.w;
        }
    }
#pragma unroll
    for (int j4 = 0; j4 < 8; ++j4) {
        ushort4 o;
        o.x = f2bf(accu[j4*4+0]); o.y = f2bf(accu[j4*4+1]);
        o.z = f2bf(accu[j4*4+2]); o.w = f2bf(accu[j4*4+3]);
        *(ushort4*)(w_out + obase + j4*4) = o;
    }
}

// ------------------------------------------------- sequential chunk scan.
// One workgroup per (b,h, 32-wide dv block); S block lives in LDS across chunks.
__global__ __launch_bounds__(256) void scan_k(
    const unsigned short* __restrict__ q, const unsigned short* __restrict__ k,
    const unsigned short* __restrict__ u, const unsigned short* __restrict__ w,
    const float* __restrict__ attn, float* __restrict__ dout)
{
    int jb = blockIdx.x & 7;
    int bh = blockIdx.x >> 3;
    int h = bh & (HH - 1), b = bh >> 2;
    __shared__ float S[DH][36];
    __shared__ float wblk[CH][68];
    __shared__ float qblk[CH][68];
    __shared__ float uadj[CH][36];
    int t = threadIdx.x;
    {
        int e = t;
#pragma unroll
        for (int j = 0; j < 32; ++j) S[e][j] = 0.0f;
    }
    __syncthreads();
    const int c = t >> 3, j0 = (t & 7) * 4;
    const int jcol = jb * 32;

    for (int ci = 0; ci < NC; ++ci) {
        size_t rowbase = (size_t)bh * LL + (size_t)ci * CH;   // for u, w, dout (B,H,L,DH)
        size_t qgbase = (size_t)b * LL + (size_t)ci * CH;     // for q, k     (B,L,D)
        ushort4 ub4 = *(const ushort4*)(u + (rowbase + c) * DH + jcol + j0);
        float ubx = bf2f(ub4.x), uby = bf2f(ub4.y), ubz = bf2f(ub4.z), ubw = bf2f(ub4.w);
        float4 accU = make_float4(0.f,0.f,0.f,0.f);
        float4 accO = make_float4(0.f,0.f,0.f,0.f);

        for (int eb = 0; eb < DH; eb += 64) {
            __syncthreads();
            for (int i = t; i < CH * 16; i += 256) {
                int r = i >> 4, c4 = (i & 15) * 4;
                ushort4 wv4 = *(const ushort4*)(w + (rowbase + r) * DH + eb + c4);
                wblk[r][c4+0] = bf2f(wv4.x); wblk[r][c4+1] = bf2f(wv4.y);
                wblk[r][c4+2] = bf2f(wv4.z); wblk[r][c4+3] = bf2f(wv4.w);
                ushort4 qv4 = *(const ushort4*)(q + (qgbase + r) * DD + h * DH + eb + c4);
                qblk[r][c4+0] = bf2f(qv4.x); qblk[r][c4+1] = bf2f(qv4.y);
                qblk[r][c4+2] = bf2f(qv4.z); qblk[r][c4+3] = bf2f(qv4.w);
            }
            __syncthreads();
            for (int e4 = 0; e4 < 64; e4 += 4) {
                float4 w4 = *(const float4*)&wblk[c][e4];
                float4 q4 = *(const float4*)&qblk[c][e4];
                int e = eb + e4;
                float ws[4] = {w4.x, w4.y, w4.z, w4.w};
                float qs[4] = {q4.x, q4.y, q4.z, q4.w};
#pragma unroll
                for (int ii = 0; ii < 4; ++ii) {
                    float4 ss = *(const float4*)&S[e + ii][j0];
                    accU.x += ws[ii]*ss.x; accU.y += ws[ii]*ss.y;
                    accU.z += ws[ii]*ss.z; accU.w += ws[ii]*ss.w;
                    accO.x += qs[ii]*ss.x; accO.y += qs[ii]*ss.y;
                    accO.z += qs[ii]*ss.z; accO.w += qs[ii]*ss.w;
                }
            }
        }
        // u_adj = u - w@S
        *(float4*)&uadj[c][j0] = make_float4(ubx - accU.x, uby - accU.y,
                                             ubz - accU.z, ubw - accU.w);
        __syncthreads();

        // out = q@S + attn@u_adj
        {
            const float* at = attn + ((size_t)bh * NC + ci) * (CH * CH) + (size_t)c * CH;
            for (int e2 = 0; e2 < CH; e2 += 4) {
                float4 a4 = *(const float4*)(at + e2);
                float as[4] = {a4.x, a4.y, a4.z, a4.w};
#pragma unroll
                for (int ii = 0; ii < 4; ++ii) {
                    float4 u4 = *(const float4*)&uadj[e2 + ii][j0];
                    accO.x += as[ii]*u4.x; accO.y += as[ii]*u4.y;
                    accO.z += as[ii]*u4.z; accO.w += as[ii]*u4.w;
                }
            }
            *(float4*)(dout + (rowbase + c) * DH + jcol + j0) = accO;
        }

        // S += k^T @ u_adj  (thread t owns S row e=t)
        {
            int e = t;
            float4 Sacc[8];
#pragma unroll
            for (int jq = 0; jq < 8; ++jq) Sacc[jq] = *(const float4*)&S[e][jq*4];
            const unsigned short* kp = k + qgbase * DD + h * DH + e;
            for (int cc = 0; cc < CH; ++cc) {
                float ke = bf2f(kp[(size_t)cc * DD]);
#pragma unroll
                for (int jq = 0; jq < 8; ++jq) {
                    float4 u4 = *(const float4*)&uadj[cc][jq*4];
                    Sacc[jq].x += ke*u4.x; Sacc[jq].y += ke*u4.y;
                    Sacc[jq].z += ke*u4.z; Sacc[jq].w += ke*u4.w;
                }
            }
#pragma unroll
            for (int jq = 0; jq < 8; ++jq) *(float4*)&S[e][jq*4] = Sacc[jq];
        }
        __syncthreads();
    }
}

// ------------------------------------------------- per-head stats (mean,var,absmean,l2)
__global__ __launch_bounds__(256) void stats_k(
    const float* __restrict__ ls, const float* __restrict__ llb,
    const float* __restrict__ dox, const float* __restrict__ v,
    float* __restrict__ stats)
{
    int bl = blockIdx.x;
    int b = bl >> 12, l = bl & (LL - 1);
    int wv = threadIdx.x >> 6, ln = threadIdx.x & 63;   // wv = head
    size_t ibase = (size_t)bl * DD + wv * DH;
    size_t dbase = (((size_t)(b * HH + wv)) * LL + l) * DH;
#pragma unroll
    for (int tn = 0; tn < 4; ++tn) {
        const float* p; size_t base;
        if (tn == 0)      { p = ls;  base = ibase; }
        else if (tn == 1) { p = llb; base = ibase; }
        else if (tn == 2) { p = dox; base = dbase; }
        else              { p = v;   base = ibase; }
        float4 x = *(const float4*)(p + base + ln * 4);
        float sm = x.x + x.y + x.z + x.w;
        float sq = x.x*x.x + x.y*x.y + x.z*x.z + x.w*x.w;
        float sa = fabsf(x.x) + fabsf(x.y) + fabsf(x.z) + fabsf(x.w);
#pragma unroll
        for (int off = 32; off > 0; off >>= 1) {
            sm += __shfl_down(sm, off);
            sq += __shfl_down(sq, off);
            sa += __shfl_down(sa, off);
        }
        if (ln == 0) {
            float mean = sm * (1.0f / DH);
            float var = sq * (1.0f / DH) - mean * mean;
            float am = sa * (1.0f / DH);
            float l2 = sqrtf(sq);
            *(float4*)(stats + (size_t)bl * 64 + wv * 16 + tn * 4) =
                make_float4(mean, var, am, l2);
        }
    }
}

// ------------------------------------------------- gate finish
__global__ __launch_bounds__(256) void gate_fin_k(
    const float* __restrict__ hpart, const float* __restrict__ stats,
    const float* __restrict__ w1, const float* __restrict__ w2,
    const float* __restrict__ b2, const float* __restrict__ ltemp,
    float* __restrict__ fw)
{
    int bl = blockIdx.x;
    int t = threadIdx.x;
    float temp = log1pf(expf(ltemp[0])) + 1e-4f;
    __shared__ float st[HH][16];
    __shared__ float red[4][4];
    if (t < 64) st[t >> 4][t & 15] = stats[(size_t)bl * 64 + t];
    const float* hp = hpart + (size_t)bl * DD;
    __syncthreads();
    for (int h = 0; h < HH; ++h) {
        float lg0=0.f, lg1=0.f, lg2=0.f, lg3=0.f;
#pragma unroll
        for (int ii = 0; ii < 4; ++ii) {
            int e = t * 4 + ii;
            float x = hp[e];
            const float* wr = w1 + (size_t)e * 1040 + 1024;
#pragma unroll
            for (int s = 0; s < 16; ++s) x += st[h][s] * wr[s];
            float g = 0.5f * x * (1.0f + erff(x * 0.70710678118654752f));
            lg0 += g * w2[e];
            lg1 += g * w2[1024 + e];
            lg2 += g * w2[2048 + e];
            lg3 += g * w2[3072 + e];
        }
#pragma unroll
        for (int off = 32; off > 0; off >>= 1) {
            lg0 += __shfl_down(lg0, off); lg1 += __shfl_down(lg1, off);
            lg2 += __shfl_down(lg2, off); lg3 += __shfl_down(lg3, off);
        }
        int wv = t >> 6, ln = t & 63;
        if (ln == 0) { red[wv][0]=lg0; red[wv][1]=lg1; red[wv][2]=lg2; red[wv][3]=lg3; }
        __syncthreads();
        if (t == 0) {
            float l0 = (red[0][0]+red[1][0]+red[2][0]+red[3][0] + b2[0]) / temp;
            float l1 = (red[0][1]+red[1][1]+red[2][1]+red[3][1] + b2[1]) / temp;
            float l2 = (red[0][2]+red[1][2]+red[2][2]+red[3][2] + b2[2]) / temp;
            float l3 = (red[0][3]+red[1][3]+red[2][3]+red[3][3] + b2[3]) / temp;
            float m = fmaxf(fmaxf(l0,l1), fmaxf(l2,l3));
            float e0 = expf(l0-m), e1 = expf(l1-m), e2 = expf(l2-m), e3 = expf(l3-m);
            float inv = 1.0f / (e0+e1+e2+e3);
            *(float4*)(fw + (size_t)bl * 16 + h * 4) =
                make_float4(e0*inv, e1*inv, e2*inv, e3*inv);
        }
        __syncthreads();
    }
}

// ------------------------------------------------- combine + rms norm
__global__ __launch_bounds__(256) void combine_k(
    const float* __restrict__ ls, const float* __restrict__ llb,
    const float* __restrict__ dox, const float* __restrict__ v,
    const float* __restrict__ fw, const float* __restrict__ rss,
    const float* __restrict__ rsl, const float* __restrict__ onw,
    float* __restrict__ opre)
{
    int h = blockIdx.x & (HH - 1);
    int bl = blockIdx.x >> 2;
    int b = bl >> 12, l = bl & (LL - 1);
    int d = threadIdx.x;
    size_t i1 = (size_t)blockIdx.x * DH + d;
    size_t i2 = (((size_t)(b * HH + h)) * LL + l) * DH + d;
    const float* fwp = fw + (size_t)blockIdx.x * 4;
    float f0 = fwp[0], f1 = fwp[1], f2 = fwp[2], f3 = fwp[3];
    float aS = rss[0], aL = rsl[0];
    float vls = ls[i1], vll = llb[i1], vd = dox[i2], vv = v[i1];
    float o = f0*vls + f1*vll + f2*vd + f3*vv + aS*vls + aL*vll;
    float s = o * o;
#pragma unroll
    for (int off = 32; off > 0; off >>= 1) s += __shfl_down(s, off);
    __shared__ float red[4];
    int wv = threadIdx.x >> 6, ln = threadIdx.x & 63;
    if (ln == 0) red[wv] = s;
    __syncthreads();
    float ms = (red[0] + red[1] + red[2] + red[3]) * (1.0f / DH);
    opre[(size_t)bl * DD + h * DH + d] = o * rsqrtf(ms + 1e-5f) * onw[d];
}

// ================================================================ launch
extern "C" void kernel_launch(void* const* d_in, const int* in_sizes, int n_in,
                              void* d_out, int out_size, void* d_ws, size_t ws_size,
                              hipStream_t stream)
{
    const float* hs  = (const float*)d_in[0];
    const float* qw  = (const float*)d_in[1];
    const float* kw  = (const float*)d_in[2];
    const float* vw  = (const float*)d_in[3];
    const float* bw  = (const float*)d_in[4];
    const float* qcw = (const float*)d_in[5];
    const float* kcw = (const float*)d_in[6];
    const float* vcw = (const float*)d_in[7];
    const float* fsw = (const float*)d_in[8];
    const float* flw = (const float*)d_in[9];
    const float* w1  = (const float*)d_in[10];
    const float* b1  = (const float*)d_in[11];
    const float* w2  = (const float*)d_in[12];
    const float* b2  = (const float*)d_in[13];
    const float* lt  = (const float*)d_in[14];
    const float* rss = (const float*)d_in[15];
    const float* rsl = (const float*)d_in[16];
    const float* onw = (const float*)d_in[17];
    const float* opw = (const float*)d_in[18];
    float* out = (float*)d_out;

    // ---- workspace layout (total ~174.7 MB) ----
    // R0: tmp f32 BLD              -> later lsbuf f32
    // R1: vbuf f32 BLD
    // R2: dbuf f32 BLD
    // R3: qbuf bf16 + kbuf bf16    -> later hpart f32 -> later opre f32
    // R4: ubuf bf16 + wbuf bf16    -> later llbuf f32
    // R5: attn f32 (1M) | stats (512K) | fw (128K) | beta (32K) floats
    float* wsf = (float*)d_ws;
    float* tmp   = wsf;
    float* vbuf  = wsf + BLD;
    float* dbuf  = wsf + 2*BLD;
    unsigned short* qbuf = (unsigned short*)(wsf + 3*BLD);
    unsigned short* kbuf = qbuf + BLD;
    float* hpart = wsf + 3*BLD;
    float* opre  = wsf + 3*BLD;
    unsigned short* ubuf = (unsigned short*)(wsf + 4*BLD);
    unsigned short* wbuf = ubuf + BLD;
    float* llbuf = wsf + 4*BLD;
    float* lsbuf = tmp;
    float* attnb = wsf + 5*BLD;
    float* statsb= attnb + (size_t)BB*HH*NC*CH*CH;   // +1,048,576
    float* fwbuf = statsb + (size_t)BL*HH*16;        // +524,288
    float* betab = fwbuf + (size_t)BL*HH*4;          // +131,072

    dim3 gg(16, 128);   // N/64, M/64

    // q/k projections + causal conv + silu + l2norm -> bf16
    gemm_nt<<<gg, 256, 0, stream>>>(hs, DD, qw, DD, nullptr, tmp, DD, BL, DD, DD);
    convnorm_qk_k<<<BL*HH, 256, 0, stream>>>(tmp, qcw, qbuf);
    gemm_nt<<<gg, 256, 0, stream>>>(hs, DD, kw, DD, nullptr, tmp, DD, BL, DD, DD);
    convnorm_qk_k<<<BL*HH, 256, 0, stream>>>(tmp, kcw, kbuf);
    // v projection + conv + silu (f32)
    gemm_nt<<<gg, 256, 0, stream>>>(hs, DD, vw, DD, nullptr, tmp, DD, BL, DD, DD);
    conv_silu_k<<<(int)(BLD/256), 256, 0, stream>>>(tmp, vcw, vbuf);

    beta_k<<<BL, 256, 0, stream>>>(hs, bw, betab);

    chunk_prep_k<<<BB*HH*NC, 256, 0, stream>>>(qbuf, kbuf, vbuf, betab, ubuf, wbuf, attnb);
    scan_k<<<BB*HH*8, 256, 0, stream>>>(qbuf, kbuf, ubuf, wbuf, attnb, dbuf);

    fir_conv_k<5><<<(int)(BLD/256), 256, 0, stream>>>(vbuf, fsw, lsbuf);
    fir_conv_k<64><<<(int)(BLD/256), 256, 0, stream>>>(vbuf, flw, llbuf);

    stats_k<<<BL, 256, 0, stream>>>(lsbuf, llbuf, dbuf, vbuf, statsb);

    // gate: hidden part (shared across heads) via GEMM with ldw=1040, +b1
    gemm_nt<<<gg, 256, 0, stream>>>(hs, DD, w1, 1040, b1, hpart, DD, BL, DD, DD);
    gate_fin_k<<<BL, 256, 0, stream>>>(hpart, statsb, w1, w2, b2, lt, fwbuf);

    combine_k<<<BL*HH, 256, 0, stream>>>(lsbuf, llbuf, dbuf, vbuf, fwbuf, rss, rsl, onw, opre);

    gemm_nt<<<gg, 256, 0, stream>>>(opre, DD, opw, DD, nullptr, out, DD, BL, DD, DD);
}

// Round 3
// 4815.469 us; speedup vs baseline: 2.3707x; 2.3707x over previous
//
#include <hip/hip_runtime.h>
#include <hip/hip_bf16.h>

#define BB 2
#define LL 4096
#define DD 1024
#define HH 4
#define DH 256
#define CH 32
#define NC (LL/CH)     // 128
#define BL (BB*LL)     // 8192
#define BLD ((size_t)BB*LL*DD) // 8388608

__device__ __forceinline__ float bf2f(unsigned short u) {
    union { float f; unsigned int i; } x; x.i = ((unsigned int)u) << 16; return x.f;
}
__device__ __forceinline__ float bflo(unsigned int u) {
    union { float f; unsigned int i; } x; x.i = u << 16; return x.f;
}
__device__ __forceinline__ float bfhi(unsigned int u) {
    union { float f; unsigned int i; } x; x.i = u & 0xFFFF0000u; return x.f;
}
__device__ __forceinline__ unsigned short f2bf(float f) {
    union { float f; unsigned int i; } x; x.f = f;
    unsigned int r = x.i + 0x7FFFu + ((x.i >> 16) & 1u);
    return (unsigned short)(r >> 16);
}

// ---------------------------------------------------------------- GEMM (NT)
__global__ __launch_bounds__(256) void gemm_nt(
    const float* __restrict__ A, int lda,
    const float* __restrict__ W, int ldw,
    const float* __restrict__ bias,
    float* __restrict__ C, int ldc,
    int M, int N, int K)
{
    __shared__ float As[16][68];
    __shared__ float Ws[16][68];
    const int t = threadIdx.x;
    const int tx = t & 15, ty = t >> 4;
    const int row0 = blockIdx.y * 64, col0 = blockIdx.x * 64;
    const int lr = t >> 2, lk = (t & 3) * 4;
    const float* Ap = A + (size_t)(row0 + lr) * lda + lk;
    const float* Wp = W + (size_t)(col0 + lr) * ldw + lk;
    float acc[4][4];
#pragma unroll
    for (int i = 0; i < 4; ++i)
#pragma unroll
        for (int j = 0; j < 4; ++j) acc[i][j] = 0.0f;

    for (int k0 = 0; k0 < K; k0 += 16) {
        float4 av = *(const float4*)(Ap + k0);
        float4 wv = *(const float4*)(Wp + k0);
        __syncthreads();
        As[lk+0][lr]=av.x; As[lk+1][lr]=av.y; As[lk+2][lr]=av.z; As[lk+3][lr]=av.w;
        Ws[lk+0][lr]=wv.x; Ws[lk+1][lr]=wv.y; Ws[lk+2][lr]=wv.z; Ws[lk+3][lr]=wv.w;
        __syncthreads();
#pragma unroll
        for (int kk = 0; kk < 16; ++kk) {
            float4 a = *(const float4*)&As[kk][ty*4];
            float4 b = *(const float4*)&Ws[kk][tx*4];
            acc[0][0] += a.x*b.x; acc[0][1] += a.x*b.y; acc[0][2] += a.x*b.z; acc[0][3] += a.x*b.w;
            acc[1][0] += a.y*b.x; acc[1][1] += a.y*b.y; acc[1][2] += a.y*b.z; acc[1][3] += a.y*b.w;
            acc[2][0] += a.z*b.x; acc[2][1] += a.z*b.y; acc[2][2] += a.z*b.z; acc[2][3] += a.z*b.w;
            acc[3][0] += a.w*b.x; acc[3][1] += a.w*b.y; acc[3][2] += a.w*b.z; acc[3][3] += a.w*b.w;
        }
    }
    const int orow = row0 + ty*4, ocol = col0 + tx*4;
    float4 bv = make_float4(0.f,0.f,0.f,0.f);
    if (bias) bv = *(const float4*)(bias + ocol);
#pragma unroll
    for (int i = 0; i < 4; ++i) {
        float4 o;
        o.x = acc[i][0] + bv.x; o.y = acc[i][1] + bv.y;
        o.z = acc[i][2] + bv.z; o.w = acc[i][3] + bv.w;
        *(float4*)(C + (size_t)(orow + i) * ldc + ocol) = o;
    }
}

// --------------------------------------- causal dwconv K=4 + silu + head-l2norm -> bf16
__global__ __launch_bounds__(256) void convnorm_qk_k(
    const float* __restrict__ x, const float* __restrict__ w,
    unsigned short* __restrict__ y)
{
    int bl = blockIdx.x >> 2;
    int h  = blockIdx.x & 3;
    int l  = bl & (LL - 1);
    int d  = threadIdx.x;
    int c  = h * DH + d;
    const float* wp = w + (size_t)c * 4;
    const float* xp = x + (size_t)bl * DD + c;
    float acc = wp[3] * xp[0];
    if (l >= 1) acc += wp[2] * xp[-(int)DD];
    if (l >= 2) acc += wp[1] * xp[-2*(int)DD];
    if (l >= 3) acc += wp[0] * xp[-3*(int)DD];
    acc = acc / (1.0f + expf(-acc));
    float s = acc * acc;
#pragma unroll
    for (int off = 32; off > 0; off >>= 1) s += __shfl_down(s, off);
    __shared__ float red[4];
    int wv = threadIdx.x >> 6, ln = threadIdx.x & 63;
    if (ln == 0) red[wv] = s;
    __syncthreads();
    float tot = red[0] + red[1] + red[2] + red[3];
    y[(size_t)bl * DD + c] = f2bf(acc * rsqrtf(tot));
}

// ------------------------------------------------- causal depthwise conv K=4 + silu (f32)
__global__ __launch_bounds__(256) void conv_silu_k(
    const float* __restrict__ x, const float* __restrict__ w, float* __restrict__ y)
{
    size_t idx = (size_t)blockIdx.x * 256 + threadIdx.x;
    int c = (int)(idx & (DD - 1));
    int bl = (int)(idx >> 10);
    int l = bl & (LL - 1);
    const float* wp = w + (size_t)c * 4;
    const float* xp = x + (size_t)bl * DD + c;
    float acc = wp[3] * xp[0];
    if (l >= 1) acc += wp[2] * xp[-(int)DD];
    if (l >= 2) acc += wp[1] * xp[-2*(int)DD];
    if (l >= 3) acc += wp[0] * xp[-3*(int)DD];
    y[idx] = acc / (1.0f + expf(-acc));
}

// ------------------------------------------------- FIR causal depthwise conv
template<int K>
__global__ __launch_bounds__(256) void fir_conv_k(
    const float* __restrict__ x, const float* __restrict__ filt, float* __restrict__ y)
{
    size_t idx = (size_t)blockIdx.x * 256 + threadIdx.x;
    int c = (int)(idx & (DD - 1));
    int bl = (int)(idx >> 10);
    int l = bl & (LL - 1);
    const float* fp = filt + (size_t)c * K;
    float acc = 0.0f;
#pragma unroll 8
    for (int tt = 0; tt < K; ++tt) {
        int ls = l - (K - 1) + tt;
        if (ls >= 0) acc += fp[tt] * x[idx + (size_t)(long)(ls - l) * DD];
    }
    y[idx] = acc;
}

// ------------------------------------------------- beta = sigmoid(hs @ b_proj^T)
__global__ __launch_bounds__(256) void beta_k(
    const float* __restrict__ hs, const float* __restrict__ bw, float* __restrict__ beta)
{
    int bl = blockIdx.x;
    const float* xr = hs + (size_t)bl * DD;
    float a0=0.f,a1=0.f,a2=0.f,a3=0.f;
    for (int k = threadIdx.x; k < DD; k += 256) {
        float xv = xr[k];
        a0 += xv * bw[k];
        a1 += xv * bw[DD + k];
        a2 += xv * bw[2*DD + k];
        a3 += xv * bw[3*DD + k];
    }
#pragma unroll
    for (int off = 32; off > 0; off >>= 1) {
        a0 += __shfl_down(a0, off); a1 += __shfl_down(a1, off);
        a2 += __shfl_down(a2, off); a3 += __shfl_down(a3, off);
    }
    __shared__ float red[4][4];
    int wv = threadIdx.x >> 6, ln = threadIdx.x & 63;
    if (ln == 0) { red[wv][0]=a0; red[wv][1]=a1; red[wv][2]=a2; red[wv][3]=a3; }
    __syncthreads();
    if (threadIdx.x < 4) {
        int h = threadIdx.x;
        float s = red[0][h] + red[1][h] + red[2][h] + red[3][h];
        beta[(size_t)bl * HH + h] = 1.0f / (1.0f + expf(-s));
    }
}

// ------------------------------------------------- k transpose: k[b,l,h*DH+e] -> kT[bh,e,l]
__global__ __launch_bounds__(256) void tr_k(
    const unsigned short* __restrict__ k, unsigned short* __restrict__ kT)
{
    int et = blockIdx.x & 3;          // e tile (4 x 64)
    int lt = (blockIdx.x >> 2) & 63;  // l tile (64 x 64)
    int bh = blockIdx.x >> 8;
    int h = bh & 3, b = bh >> 2;
    __shared__ unsigned short tile[64][72];
    int t = threadIdx.x;
    int tr = t >> 4;            // 0..15
    int tc = (t & 15) * 4;      // 0..60
#pragma unroll
    for (int i = 0; i < 4; ++i) {
        int l = tr + i * 16;
        ushort4 v = *(const ushort4*)(k + ((size_t)b * LL + lt*64 + l) * DD + h * DH + et*64 + tc);
        *(ushort4*)&tile[l][tc] = v;
    }
    __syncthreads();
#pragma unroll
    for (int i = 0; i < 4; ++i) {
        int e = tr + i * 16;
        ushort4 v;
        v.x = tile[tc+0][e]; v.y = tile[tc+1][e];
        v.z = tile[tc+2][e]; v.w = tile[tc+3][e];
        *(ushort4*)(kT + ((size_t)bh * DH + et*64 + e) * LL + (size_t)lt*64 + tc) = v;
    }
}

// ------------------------------------------------- per-chunk prep (unchanged from R2)
__global__ __launch_bounds__(256) void chunk_prep_k(
    const unsigned short* __restrict__ q, const unsigned short* __restrict__ k,
    const float* __restrict__ v, const float* __restrict__ beta,
    unsigned short* __restrict__ u_out, unsigned short* __restrict__ w_out,
    float* __restrict__ attn_out)
{
    int ci = blockIdx.x & (NC - 1);
    int bh = blockIdx.x >> 7;
    int h = bh & (HH - 1), b = bh >> 2;
    __shared__ float kt[CH][DH + 4];
    __shared__ float Am[CH][CH + 1];
    __shared__ float Ab[CH][CH + 1];
    __shared__ float bet[CH];
    int t = threadIdx.x;
    size_t qgbase = (size_t)b * LL + (size_t)ci * CH;

    for (int i = t; i < CH * (DH / 4); i += 256) {
        int r = i >> 6;
        int c4 = (i & 63) * 4;
        ushort4 kv = *(const ushort4*)(k + (qgbase + r) * DD + h * DH + c4);
        kt[r][c4+0] = bf2f(kv.x); kt[r][c4+1] = bf2f(kv.y);
        kt[r][c4+2] = bf2f(kv.z); kt[r][c4+3] = bf2f(kv.w);
    }
    if (t < CH) bet[t] = beta[(qgbase + t) * HH + h];
    __syncthreads();

    int c = t >> 3, e0 = (t & 7) * 4;
    {
        float accA[4] = {0,0,0,0}, accT[4] = {0,0,0,0};
        const unsigned short* qrow = q + (qgbase + c) * DD + h * DH;
        for (int d0 = 0; d0 < DH; d0 += 4) {
            float4 kc = *(const float4*)&kt[c][d0];
            ushort4 qv = *(const ushort4*)(qrow + d0);
            float qx = bf2f(qv.x), qy = bf2f(qv.y), qz = bf2f(qv.z), qw = bf2f(qv.w);
#pragma unroll
            for (int e = 0; e < 4; ++e) {
                float4 ke = *(const float4*)&kt[e0 + e][d0];
                accA[e] += kc.x*ke.x + kc.y*ke.y + kc.z*ke.z + kc.w*ke.w;
                accT[e] += qx*ke.x + qy*ke.y + qz*ke.z + qw*ke.w;
            }
        }
        float bc = bet[c];
        size_t abase = (size_t)blockIdx.x * (CH * CH) + (size_t)c * CH;
#pragma unroll
        for (int e = 0; e < 4; ++e) {
            int ee = e0 + e;
            Am[c][ee] = (ee < c) ? (-bc * accA[e]) : 0.0f;
            attn_out[abase + ee] = (ee <= c) ? accT[e] : 0.0f;
        }
    }
    __syncthreads();

    for (int i = 1; i < CH; ++i) {
        float upd = 0.0f;
        if (t < i) {
#pragma unroll
            for (int kk = 0; kk < CH; ++kk) upd += Am[i][kk] * Am[kk][t];
        }
        __syncthreads();
        if (t < i) Am[i][t] += upd;
        __syncthreads();
    }

    for (int i = t; i < CH * CH; i += 256) {
        int cc = i >> 5, ee = i & 31;
        float val = Am[cc][ee] + (cc == ee ? 1.0f : 0.0f);
        Ab[cc][ee] = val * bet[ee];
    }
    __syncthreads();

    int c2 = t >> 3, dd0 = (t & 7) * 32;
    float accu[32];
#pragma unroll
    for (int j = 0; j < 32; ++j) accu[j] = 0.0f;
    for (int e = 0; e < CH; ++e) {
        float ab = Ab[c2][e];
        const float* vrow = v + (qgbase + e) * DD + h * DH + dd0;
#pragma unroll
        for (int j4 = 0; j4 < 8; ++j4) {
            float4 v4 = *(const float4*)(vrow + j4 * 4);
            accu[j4*4+0] += ab * v4.x; accu[j4*4+1] += ab * v4.y;
            accu[j4*4+2] += ab * v4.z; accu[j4*4+3] += ab * v4.w;
        }
    }
    size_t obase = ((size_t)bh * LL + (size_t)ci * CH + c2) * DH + dd0;
#pragma unroll
    for (int j4 = 0; j4 < 8; ++j4) {
        ushort4 o;
        o.x = f2bf(accu[j4*4+0]); o.y = f2bf(accu[j4*4+1]);
        o.z = f2bf(accu[j4*4+2]); o.w = f2bf(accu[j4*4+3]);
        *(ushort4*)(u_out + obase + j4*4) = o;
    }

#pragma unroll
    for (int j = 0; j < 32; ++j) accu[j] = 0.0f;
    for (int e = 0; e < CH; ++e) {
        float ab = Ab[c2][e];
#pragma unroll
        for (int j4 = 0; j4 < 8; ++j4) {
            float4 v4 = *(const float4*)&kt[e][dd0 + j4*4];
            accu[j4*4+0] += ab * v4.x; accu[j4*4+1] += ab * v4.y;
            accu[j4*4+2] += ab * v4.z; accu[j4*4+3] += ab * v4.w;
        }
    }
#pragma unroll
    for (int j4 = 0; j4 < 8; ++j4) {
        ushort4 o;
        o.x = f2bf(accu[j4*4+0]); o.y = f2bf(accu[j4*4+1]);
        o.z = f2bf(accu[j4*4+2]); o.w = f2bf(accu[j4*4+3]);
        *(ushort4*)(w_out + obase + j4*4) = o;
    }
}

// ------------------------------------------------- chunk scan v2.
// grid = (b,h) x 16 col-blocks of 16 dv cols. 256 threads.
// S[256][20] f32 in LDS persists across 128 chunks.
// thread roles: stage1/attn: (c = t>>3, j0 = (t&7)*2); update: e = t.
__global__ __launch_bounds__(256) void scan2_k(
    const unsigned short* __restrict__ q, const unsigned short* __restrict__ kT,
    const unsigned short* __restrict__ u, const unsigned short* __restrict__ w,
    const float* __restrict__ attn, float* __restrict__ dout)
{
    const int jb = blockIdx.x & 15;
    const int bh = blockIdx.x >> 4;
    const int h = bh & (HH - 1), b = bh >> 2;
    const int jcol = jb * 16;
    __shared__ float S[DH][20];      // stride 20: float4-aligned rows, banks tile cleanly
    __shared__ float uadj[CH][20];
    const int t = threadIdx.x;
    const int c  = t >> 3;
    const int j0 = (t & 7) * 2;

    for (int i = t; i < DH * 20; i += 256) (&S[0][0])[i] = 0.0f;
    __syncthreads();

    const unsigned short* kTrow = kT + ((size_t)bh * DH + t) * LL;

    for (int ci = 0; ci < NC; ++ci) {
        const size_t rowbase = (size_t)bh * LL + (size_t)ci * CH;
        const size_t qgbase  = (size_t)b  * LL + (size_t)ci * CH;

        // prefetch this chunk's u element and k row (per-thread, 1 cache line)
        ushort2 uv2 = *(const ushort2*)(u + (rowbase + c) * DH + jcol + j0);
        const uint4* ktp = (const uint4*)(kTrow + (size_t)ci * CH);
        uint4 kt0 = ktp[0], kt1 = ktp[1], kt2 = ktp[2], kt3 = ktp[3];

        // ---- stage 1: T1 = w@S, T2 = q@S for this thread's (c, j0..j0+1)
        const uint4* wp = (const uint4*)(w + (rowbase + c) * DH);
        const uint4* qp = (const uint4*)(q + (qgbase + c) * DD + h * DH);
        float t1al=0, t1bl=0, t2al=0, t2bl=0;   // from even e (lo halves)
        float t1ah=0, t1bh=0, t2ah=0, t2bh=0;   // from odd e (hi halves)
        for (int eb = 0; eb < 32; ++eb) {       // 8 bf16 per iteration
            uint4 wv = wp[eb];
            uint4 qv = qp[eb];
            unsigned wu[4] = {wv.x, wv.y, wv.z, wv.w};
            unsigned qu[4] = {qv.x, qv.y, qv.z, qv.w};
            int e0 = eb * 8;
#pragma unroll
            for (int p = 0; p < 4; ++p) {
                int e = e0 + p * 2;
                float2 s0 = *(const float2*)&S[e][j0];
                float2 s1 = *(const float2*)&S[e + 1][j0];
                float wlo = bflo(wu[p]), whi = bfhi(wu[p]);
                float qlo = bflo(qu[p]), qhi = bfhi(qu[p]);
                t1al += wlo * s0.x; t1bl += wlo * s0.y;
                t2al += qlo * s0.x; t2bl += qlo * s0.y;
                t1ah += whi * s1.x; t1bh += whi * s1.y;
                t2ah += qhi * s1.x; t2bh += qhi * s1.y;
            }
        }
        float ua = bf2f(uv2.x) - (t1al + t1ah);
        float ub = bf2f(uv2.y) - (t1bl + t1bh);
        float oa = t2al + t2ah;
        float ob = t2bl + t2bh;
        *(float2*)&uadj[c][j0] = make_float2(ua, ub);
        __syncthreads();

        // ---- out = q@S + attn@u_adj  (attn row c: 8 lanes share -> dedup)
        {
            const float* at = attn + ((size_t)bh * NC + ci) * (CH * CH) + (size_t)c * CH;
#pragma unroll
            for (int q4 = 0; q4 < 8; ++q4) {
                float4 a4 = *(const float4*)(at + q4 * 4);
                int cc = q4 * 4;
                float2 u0 = *(const float2*)&uadj[cc + 0][j0];
                float2 u1 = *(const float2*)&uadj[cc + 1][j0];
                float2 u2 = *(const float2*)&uadj[cc + 2][j0];
                float2 u3 = *(const float2*)&uadj[cc + 3][j0];
                oa += a4.x*u0.x + a4.y*u1.x + a4.z*u2.x + a4.w*u3.x;
                ob += a4.x*u0.y + a4.y*u1.y + a4.z*u2.y + a4.w*u3.y;
            }
            *(float2*)(dout + (rowbase + c) * DH + jcol + j0) = make_float2(oa, ob);
        }

        // ---- S[e=t][:] += sum_cc k[cc][e] * uadj[cc][:]
        {
            float4 s0 = *(const float4*)&S[t][0];
            float4 s1 = *(const float4*)&S[t][4];
            float4 s2 = *(const float4*)&S[t][8];
            float4 s3 = *(const float4*)&S[t][12];
            unsigned karr[16] = {kt0.x, kt0.y, kt0.z, kt0.w,
                                 kt1.x, kt1.y, kt1.z, kt1.w,
                                 kt2.x, kt2.y, kt2.z, kt2.w,
                                 kt3.x, kt3.y, kt3.z, kt3.w};
#pragma unroll
            for (int cc = 0; cc < CH; ++cc) {
                unsigned uu = karr[cc >> 1];
                float kv = (cc & 1) ? bfhi(uu) : bflo(uu);
                float4 u0 = *(const float4*)&uadj[cc][0];
                float4 u1 = *(const float4*)&uadj[cc][4];
                float4 u2 = *(const float4*)&uadj[cc][8];
                float4 u3 = *(const float4*)&uadj[cc][12];
                s0.x += kv*u0.x; s0.y += kv*u0.y; s0.z += kv*u0.z; s0.w += kv*u0.w;
                s1.x += kv*u1.x; s1.y += kv*u1.y; s1.z += kv*u1.z; s1.w += kv*u1.w;
                s2.x += kv*u2.x; s2.y += kv*u2.y; s2.z += kv*u2.z; s2.w += kv*u2.w;
                s3.x += kv*u3.x; s3.y += kv*u3.y; s3.z += kv*u3.z; s3.w += kv*u3.w;
            }
            *(float4*)&S[t][0]  = s0;
            *(float4*)&S[t][4]  = s1;
            *(float4*)&S[t][8]  = s2;
            *(float4*)&S[t][12] = s3;
        }
        __syncthreads();
    }
}

// ------------------------------------------------- per-head stats
__global__ __launch_bounds__(256) void stats_k(
    const float* __restrict__ ls, const float* __restrict__ llb,
    const float* __restrict__ dox, const float* __restrict__ v,
    float* __restrict__ stats)
{
    int bl = blockIdx.x;
    int b = bl >> 12, l = bl & (LL - 1);
    int wv = threadIdx.x >> 6, ln = threadIdx.x & 63;
    size_t ibase = (size_t)bl * DD + wv * DH;
    size_t dbase = (((size_t)(b * HH + wv)) * LL + l) * DH;
#pragma unroll
    for (int tn = 0; tn < 4; ++tn) {
        const float* p; size_t base;
        if (tn == 0)      { p = ls;  base = ibase; }
        else if (tn == 1) { p = llb; base = ibase; }
        else if (tn == 2) { p = dox; base = dbase; }
        else              { p = v;   base = ibase; }
        float4 x = *(const float4*)(p + base + ln * 4);
        float sm = x.x + x.y + x.z + x.w;
        float sq = x.x*x.x + x.y*x.y + x.z*x.z + x.w*x.w;
        float sa = fabsf(x.x) + fabsf(x.y) + fabsf(x.z) + fabsf(x.w);
#pragma unroll
        for (int off = 32; off > 0; off >>= 1) {
            sm += __shfl_down(sm, off);
            sq += __shfl_down(sq, off);
            sa += __shfl_down(sa, off);
        }
        if (ln == 0) {
            float mean = sm * (1.0f / DH);
            float var = sq * (1.0f / DH) - mean * mean;
            float am = sa * (1.0f / DH);
            float l2 = sqrtf(sq);
            *(float4*)(stats + (size_t)bl * 64 + wv * 16 + tn * 4) =
                make_float4(mean, var, am, l2);
        }
    }
}

// ------------------------------------------------- gate finish
__global__ __launch_bounds__(256) void gate_fin_k(
    const float* __restrict__ hpart, const float* __restrict__ stats,
    const float* __restrict__ w1, const float* __restrict__ w2,
    const float* __restrict__ b2, const float* __restrict__ ltemp,
    float* __restrict__ fw)
{
    int bl = blockIdx.x;
    int t = threadIdx.x;
    float temp = log1pf(expf(ltemp[0])) + 1e-4f;
    __shared__ float st[HH][16];
    __shared__ float red[4][4];
    if (t < 64) st[t >> 4][t & 15] = stats[(size_t)bl * 64 + t];
    const float* hp = hpart + (size_t)bl * DD;
    __syncthreads();
    for (int h = 0; h < HH; ++h) {
        float lg0=0.f, lg1=0.f, lg2=0.f, lg3=0.f;
#pragma unroll
        for (int ii = 0; ii < 4; ++ii) {
            int e = t * 4 + ii;
            float x = hp[e];
            const float* wr = w1 + (size_t)e * 1040 + 1024;
#pragma unroll
            for (int s = 0; s < 16; ++s) x += st[h][s] * wr[s];
            float g = 0.5f * x * (1.0f + erff(x * 0.70710678118654752f));
            lg0 += g * w2[e];
            lg1 += g * w2[1024 + e];
            lg2 += g * w2[2048 + e];
            lg3 += g * w2[3072 + e];
        }
#pragma unroll
        for (int off = 32; off > 0; off >>= 1) {
            lg0 += __shfl_down(lg0, off); lg1 += __shfl_down(lg1, off);
            lg2 += __shfl_down(lg2, off); lg3 += __shfl_down(lg3, off);
        }
        int wv = t >> 6, ln = t & 63;
        if (ln == 0) { red[wv][0]=lg0; red[wv][1]=lg1; red[wv][2]=lg2; red[wv][3]=lg3; }
        __syncthreads();
        if (t == 0) {
            float l0 = (red[0][0]+red[1][0]+red[2][0]+red[3][0] + b2[0]) / temp;
            float l1 = (red[0][1]+red[1][1]+red[2][1]+red[3][1] + b2[1]) / temp;
            float l2 = (red[0][2]+red[1][2]+red[2][2]+red[3][2] + b2[2]) / temp;
            float l3 = (red[0][3]+red[1][3]+red[2][3]+red[3][3] + b2[3]) / temp;
            float m = fmaxf(fmaxf(l0,l1), fmaxf(l2,l3));
            float e0 = expf(l0-m), e1 = expf(l1-m), e2 = expf(l2-m), e3 = expf(l3-m);
            float inv = 1.0f / (e0+e1+e2+e3);
            *(float4*)(fw + (size_t)bl * 16 + h * 4) =
                make_float4(e0*inv, e1*inv, e2*inv, e3*inv);
        }
        __syncthreads();
    }
}

// ------------------------------------------------- combine + rms norm
__global__ __launch_bounds__(256) void combine_k(
    const float* __restrict__ ls, const float* __restrict__ llb,
    const float* __restrict__ dox, const float* __restrict__ v,
    const float* __restrict__ fw, const float* __restrict__ rss,
    const float* __restrict__ rsl, const float* __restrict__ onw,
    float* __restrict__ opre)
{
    int h = blockIdx.x & (HH - 1);
    int bl = blockIdx.x >> 2;
    int b = bl >> 12, l = bl & (LL - 1);
    int d = threadIdx.x;
    size_t i1 = (size_t)blockIdx.x * DH + d;
    size_t i2 = (((size_t)(b * HH + h)) * LL + l) * DH + d;
    const float* fwp = fw + (size_t)blockIdx.x * 4;
    float f0 = fwp[0], f1 = fwp[1], f2 = fwp[2], f3 = fwp[3];
    float aS = rss[0], aL = rsl[0];
    float vls = ls[i1], vll = llb[i1], vd = dox[i2], vv = v[i1];
    float o = f0*vls + f1*vll + f2*vd + f3*vv + aS*vls + aL*vll;
    float s = o * o;
#pragma unroll
    for (int off = 32; off > 0; off >>= 1) s += __shfl_down(s, off);
    __shared__ float red[4];
    int wv = threadIdx.x >> 6, ln = threadIdx.x & 63;
    if (ln == 0) red[wv] = s;
    __syncthreads();
    float ms = (red[0] + red[1] + red[2] + red[3]) * (1.0f / DH);
    opre[(size_t)bl * DD + h * DH + d] = o * rsqrtf(ms + 1e-5f) * onw[d];
}

// ================================================================ launch
extern "C" void kernel_launch(void* const* d_in, const int* in_sizes, int n_in,
                              void* d_out, int out_size, void* d_ws, size_t ws_size,
                              hipStream_t stream)
{
    const float* hs  = (const float*)d_in[0];
    const float* qw  = (const float*)d_in[1];
    const float* kw  = (const float*)d_in[2];
    const float* vw  = (const float*)d_in[3];
    const float* bw  = (const float*)d_in[4];
    const float* qcw = (const float*)d_in[5];
    const float* kcw = (const float*)d_in[6];
    const float* vcw = (const float*)d_in[7];
    const float* fsw = (const float*)d_in[8];
    const float* flw = (const float*)d_in[9];
    const float* w1  = (const float*)d_in[10];
    const float* b1  = (const float*)d_in[11];
    const float* w2  = (const float*)d_in[12];
    const float* b2  = (const float*)d_in[13];
    const float* lt  = (const float*)d_in[14];
    const float* rss = (const float*)d_in[15];
    const float* rsl = (const float*)d_in[16];
    const float* onw = (const float*)d_in[17];
    const float* opw = (const float*)d_in[18];
    float* out = (float*)d_out;

    // workspace layout (~175 MB as in R2; kT (16MB bf16) lives in tmp region,
    // free between v-conv and fir<5>)
    float* wsf = (float*)d_ws;
    float* tmp   = wsf;
    float* vbuf  = wsf + BLD;
    float* dbuf  = wsf + 2*BLD;
    unsigned short* qbuf = (unsigned short*)(wsf + 3*BLD);
    unsigned short* kbuf = qbuf + BLD;
    float* hpart = wsf + 3*BLD;
    float* opre  = wsf + 3*BLD;
    unsigned short* ubuf = (unsigned short*)(wsf + 4*BLD);
    unsigned short* wbuf = ubuf + BLD;
    float* llbuf = wsf + 4*BLD;
    float* lsbuf = tmp;
    unsigned short* ktbuf = (unsigned short*)tmp;
    float* attnb = wsf + 5*BLD;
    float* statsb= attnb + (size_t)BB*HH*NC*CH*CH;
    float* fwbuf = statsb + (size_t)BL*HH*16;
    float* betab = fwbuf + (size_t)BL*HH*4;

    dim3 gg(16, 128);

    gemm_nt<<<gg, 256, 0, stream>>>(hs, DD, qw, DD, nullptr, tmp, DD, BL, DD, DD);
    convnorm_qk_k<<<BL*HH, 256, 0, stream>>>(tmp, qcw, qbuf);
    gemm_nt<<<gg, 256, 0, stream>>>(hs, DD, kw, DD, nullptr, tmp, DD, BL, DD, DD);
    convnorm_qk_k<<<BL*HH, 256, 0, stream>>>(tmp, kcw, kbuf);
    gemm_nt<<<gg, 256, 0, stream>>>(hs, DD, vw, DD, nullptr, tmp, DD, BL, DD, DD);
    conv_silu_k<<<(int)(BLD/256), 256, 0, stream>>>(tmp, vcw, vbuf);

    beta_k<<<BL, 256, 0, stream>>>(hs, bw, betab);

    // kT[bh][e][l] for the scan's S-update (tmp region is free now)
    tr_k<<<8*64*4, 256, 0, stream>>>(kbuf, ktbuf);

    chunk_prep_k<<<BB*HH*NC, 256, 0, stream>>>(qbuf, kbuf, vbuf, betab, ubuf, wbuf, attnb);
    scan2_k<<<BB*HH*16, 256, 0, stream>>>(qbuf, ktbuf, ubuf, wbuf, attnb, dbuf);

    fir_conv_k<5><<<(int)(BLD/256), 256, 0, stream>>>(vbuf, fsw, lsbuf);
    fir_conv_k<64><<<(int)(BLD/256), 256, 0, stream>>>(vbuf, flw, llbuf);

    stats_k<<<BL, 256, 0, stream>>>(lsbuf, llbuf, dbuf, vbuf, statsb);

    gemm_nt<<<gg, 256, 0, stream>>>(hs, DD, w1, 1040, b1, hpart, DD, BL, DD, DD);
    gate_fin_k<<<BL, 256, 0, stream>>>(hpart, statsb, w1, w2, b2, lt, fwbuf);

    combine_k<<<BL*HH, 256, 0, stream>>>(lsbuf, llbuf, dbuf, vbuf, fwbuf, rss, rsl, onw, opre);

    gemm_nt<<<gg, 256, 0, stream>>>(opre, DD, opw, DD, nullptr, out, DD, BL, DD, DD);
}

// Round 4
// 2444.893 us; speedup vs baseline: 4.6693x; 1.9696x over previous
//
#include <hip/hip_runtime.h>
#include <hip/hip_bf16.h>

#define BB 2
#define LL 4096
#define DD 1024
#define HH 4
#define DH 256
#define CH 32
#define NC (LL/CH)     // 128
#define BL (BB*LL)     // 8192
#define BLD ((size_t)BB*LL*DD) // 8388608

typedef __attribute__((ext_vector_type(8))) short short8;
typedef __attribute__((ext_vector_type(4))) float floatx4;

__device__ __forceinline__ float bf2f(unsigned short u) {
    union { float f; unsigned int i; } x; x.i = ((unsigned int)u) << 16; return x.f;
}
__device__ __forceinline__ float bflo(unsigned int u) {
    union { float f; unsigned int i; } x; x.i = u << 16; return x.f;
}
__device__ __forceinline__ float bfhi(unsigned int u) {
    union { float f; unsigned int i; } x; x.i = u & 0xFFFF0000u; return x.f;
}
__device__ __forceinline__ unsigned short f2bf(float f) {
    union { float f; unsigned int i; } x; x.f = f;
    unsigned int r = x.i + 0x7FFFu + ((x.i >> 16) & 1u);
    return (unsigned short)(r >> 16);
}

// ---------------------------------------------------------------- bf16 MFMA GEMM (NT)
// C[M,N] f32 = A[M,K] f32 @ W[N,K]^T f32 (+bias), inputs converted to bf16 in staging.
// 128x128 tile, 256 threads = 4 waves in 2x2, each wave 64x64 via 4x4 mfma_16x16x32.
__global__ __launch_bounds__(256) void gemm_mfma(
    const float* __restrict__ A, int lda,
    const float* __restrict__ W, int ldw,
    const float* __restrict__ bias,
    float* __restrict__ C, int ldc, int K)
{
    __shared__ unsigned short Abuf[128][56];   // 56-short stride: 16B-aligned rows, <=2-way banks
    __shared__ unsigned short Bbuf[128][56];
    const int t = threadIdx.x;
    const int wave = t >> 6, lane = t & 63;
    const int wm = wave >> 1, wn = wave & 1;
    const int row0 = blockIdx.y * 128, col0 = blockIdx.x * 128;

    floatx4 acc[4][4];
#pragma unroll
    for (int i = 0; i < 4; ++i)
#pragma unroll
        for (int j = 0; j < 4; ++j) acc[i][j] = (floatx4){0.f, 0.f, 0.f, 0.f};

    const int fr = lane & 15, fk = (lane >> 4) * 8;

    for (int kt = 0; kt < K; kt += 32) {
        __syncthreads();
#pragma unroll
        for (int it = 0; it < 2; ++it) {
            int idx = t + it * 256;          // 0..511 over 128 rows x 4 chunks of 8
            int r = idx >> 2, s = (idx & 3) * 8;
            const float* ap = A + (size_t)(row0 + r) * lda + kt + s;
            float4 a0 = *(const float4*)(ap);
            float4 a1 = *(const float4*)(ap + 4);
            ushort4 p0, p1;
            p0.x = f2bf(a0.x); p0.y = f2bf(a0.y); p0.z = f2bf(a0.z); p0.w = f2bf(a0.w);
            p1.x = f2bf(a1.x); p1.y = f2bf(a1.y); p1.z = f2bf(a1.z); p1.w = f2bf(a1.w);
            *(ushort4*)&Abuf[r][s]     = p0;
            *(ushort4*)&Abuf[r][s + 4] = p1;
            const float* wp = W + (size_t)(col0 + r) * ldw + kt + s;
            float4 b0 = *(const float4*)(wp);
            float4 b1 = *(const float4*)(wp + 4);
            ushort4 q0, q1;
            q0.x = f2bf(b0.x); q0.y = f2bf(b0.y); q0.z = f2bf(b0.z); q0.w = f2bf(b0.w);
            q1.x = f2bf(b1.x); q1.y = f2bf(b1.y); q1.z = f2bf(b1.z); q1.w = f2bf(b1.w);
            *(ushort4*)&Bbuf[r][s]     = q0;
            *(ushort4*)&Bbuf[r][s + 4] = q1;
        }
        __syncthreads();

        short8 afrag[4], bfrag[4];
#pragma unroll
        for (int i = 0; i < 4; ++i) {
            afrag[i] = *(const short8*)&Abuf[wm * 64 + i * 16 + fr][fk];
            bfrag[i] = *(const short8*)&Bbuf[wn * 64 + i * 16 + fr][fk];
        }
#pragma unroll
        for (int i = 0; i < 4; ++i)
#pragma unroll
            for (int j = 0; j < 4; ++j)
                acc[i][j] = __builtin_amdgcn_mfma_f32_16x16x32_bf16(
                    afrag[i], bfrag[j], acc[i][j], 0, 0, 0);
    }

    const int fc = lane & 15, frow = (lane >> 4) * 4;
#pragma unroll
    for (int j = 0; j < 4; ++j) {
        int col = col0 + wn * 64 + j * 16 + fc;
        float bv = bias ? bias[col] : 0.0f;
#pragma unroll
        for (int i = 0; i < 4; ++i) {
#pragma unroll
            for (int r = 0; r < 4; ++r) {
                int row = row0 + wm * 64 + i * 16 + frow + r;
                C[(size_t)row * ldc + col] = acc[i][j][r] + bv;
            }
        }
    }
}

// --------------------------------------- causal dwconv K=4 + silu + head-l2norm -> bf16
__global__ __launch_bounds__(256) void convnorm_qk_k(
    const float* __restrict__ x, const float* __restrict__ w,
    unsigned short* __restrict__ y)
{
    int bl = blockIdx.x >> 2;
    int h  = blockIdx.x & 3;
    int l  = bl & (LL - 1);
    int d  = threadIdx.x;
    int c  = h * DH + d;
    const float* wp = w + (size_t)c * 4;
    const float* xp = x + (size_t)bl * DD + c;
    float acc = wp[3] * xp[0];
    if (l >= 1) acc += wp[2] * xp[-(int)DD];
    if (l >= 2) acc += wp[1] * xp[-2*(int)DD];
    if (l >= 3) acc += wp[0] * xp[-3*(int)DD];
    acc = acc / (1.0f + expf(-acc));
    float s = acc * acc;
#pragma unroll
    for (int off = 32; off > 0; off >>= 1) s += __shfl_down(s, off);
    __shared__ float red[4];
    int wv = threadIdx.x >> 6, ln = threadIdx.x & 63;
    if (ln == 0) red[wv] = s;
    __syncthreads();
    float tot = red[0] + red[1] + red[2] + red[3];
    y[(size_t)bl * DD + c] = f2bf(acc * rsqrtf(tot));
}

// ------------------------------------------------- causal depthwise conv K=4 + silu (f32)
__global__ __launch_bounds__(256) void conv_silu_k(
    const float* __restrict__ x, const float* __restrict__ w, float* __restrict__ y)
{
    size_t idx = (size_t)blockIdx.x * 256 + threadIdx.x;
    int c = (int)(idx & (DD - 1));
    int bl = (int)(idx >> 10);
    int l = bl & (LL - 1);
    const float* wp = w + (size_t)c * 4;
    const float* xp = x + (size_t)bl * DD + c;
    float acc = wp[3] * xp[0];
    if (l >= 1) acc += wp[2] * xp[-(int)DD];
    if (l >= 2) acc += wp[1] * xp[-2*(int)DD];
    if (l >= 3) acc += wp[0] * xp[-3*(int)DD];
    y[idx] = acc / (1.0f + expf(-acc));
}

// ------------------------------------------------- FIR causal depthwise conv, LDS-tiled.
// grid: b (2) x ltile (64) x ctile (16); block 256. Each thread: 1 channel, 16 outputs.
template<int K>
__global__ __launch_bounds__(256) void fir2_k(
    const float* __restrict__ x, const float* __restrict__ filt, float* __restrict__ y)
{
    const int ctile = blockIdx.x & 15;
    const int ltile = (blockIdx.x >> 4) & 63;
    const int b = blockIdx.x >> 10;
    const int RT = 64 + K - 1;
    __shared__ float xs[RT][64];
    __shared__ float fs[64][K + 1];
    const int t = threadIdx.x;
    const int l0 = ltile * 64;

    for (int i = t; i < RT * 16; i += 256) {
        int li = i >> 4, c4 = (i & 15) * 4;
        int l = l0 - (K - 1) + li;
        float4 v = make_float4(0.f, 0.f, 0.f, 0.f);
        if (l >= 0)
            v = *(const float4*)(x + ((size_t)b * LL + l) * DD + ctile * 64 + c4);
        *(float4*)&xs[li][c4] = v;
    }
    for (int i = t; i < 64 * K; i += 256) {
        fs[i / K][i % K] = filt[(size_t)ctile * 64 * K + i];
    }
    __syncthreads();

    const int c = t & 63, lg = t >> 6;
    float acc[16];
#pragma unroll
    for (int o = 0; o < 16; ++o) acc[o] = 0.f;
#pragma unroll
    for (int j = 0; j < 16 + K - 1; ++j) {
        float xv = xs[lg * 16 + j][c];
#pragma unroll
        for (int o = 0; o < 16; ++o) {
            int tap = j - o;
            if (tap >= 0 && tap < K) acc[o] += fs[c][tap] * xv;
        }
    }
    size_t base = ((size_t)b * LL + l0 + lg * 16) * DD + ctile * 64 + c;
#pragma unroll
    for (int o = 0; o < 16; ++o)
        y[base + (size_t)o * DD] = acc[o];
}

// ------------------------------------------------- beta = sigmoid(hs @ b_proj^T)
__global__ __launch_bounds__(256) void beta_k(
    const float* __restrict__ hs, const float* __restrict__ bw, float* __restrict__ beta)
{
    int bl = blockIdx.x;
    const float* xr = hs + (size_t)bl * DD;
    float a0=0.f,a1=0.f,a2=0.f,a3=0.f;
    for (int k = threadIdx.x; k < DD; k += 256) {
        float xv = xr[k];
        a0 += xv * bw[k];
        a1 += xv * bw[DD + k];
        a2 += xv * bw[2*DD + k];
        a3 += xv * bw[3*DD + k];
    }
#pragma unroll
    for (int off = 32; off > 0; off >>= 1) {
        a0 += __shfl_down(a0, off); a1 += __shfl_down(a1, off);
        a2 += __shfl_down(a2, off); a3 += __shfl_down(a3, off);
    }
    __shared__ float red[4][4];
    int wv = threadIdx.x >> 6, ln = threadIdx.x & 63;
    if (ln == 0) { red[wv][0]=a0; red[wv][1]=a1; red[wv][2]=a2; red[wv][3]=a3; }
    __syncthreads();
    if (threadIdx.x < 4) {
        int h = threadIdx.x;
        float s = red[0][h] + red[1][h] + red[2][h] + red[3][h];
        beta[(size_t)bl * HH + h] = 1.0f / (1.0f + expf(-s));
    }
}

// ------------------------------------------------- k transpose: k[b,l,h*DH+e] -> kT[bh,e,l]
__global__ __launch_bounds__(256) void tr_k(
    const unsigned short* __restrict__ k, unsigned short* __restrict__ kT)
{
    int et = blockIdx.x & 3;
    int lt = (blockIdx.x >> 2) & 63;
    int bh = blockIdx.x >> 8;
    int h = bh & 3, b = bh >> 2;
    __shared__ unsigned short tile[64][72];
    int t = threadIdx.x;
    int tr = t >> 4;
    int tc = (t & 15) * 4;
#pragma unroll
    for (int i = 0; i < 4; ++i) {
        int l = tr + i * 16;
        ushort4 v = *(const ushort4*)(k + ((size_t)b * LL + lt*64 + l) * DD + h * DH + et*64 + tc);
        *(ushort4*)&tile[l][tc] = v;
    }
    __syncthreads();
#pragma unroll
    for (int i = 0; i < 4; ++i) {
        int e = tr + i * 16;
        ushort4 v;
        v.x = tile[tc+0][e]; v.y = tile[tc+1][e];
        v.z = tile[tc+2][e]; v.w = tile[tc+3][e];
        *(ushort4*)(kT + ((size_t)bh * DH + et*64 + e) * LL + (size_t)lt*64 + tc) = v;
    }
}

// ------------------------------------------------- per-chunk prep
__global__ __launch_bounds__(256) void chunk_prep_k(
    const unsigned short* __restrict__ q, const unsigned short* __restrict__ k,
    const float* __restrict__ v, const float* __restrict__ beta,
    unsigned short* __restrict__ u_out, unsigned short* __restrict__ w_out,
    float* __restrict__ attn_out)
{
    int ci = blockIdx.x & (NC - 1);
    int bh = blockIdx.x >> 7;
    int h = bh & (HH - 1), b = bh >> 2;
    __shared__ float kt[CH][DH + 4];
    __shared__ float Am[CH][CH + 1];
    __shared__ float Ab[CH][CH + 1];
    __shared__ float bet[CH];
    int t = threadIdx.x;
    size_t qgbase = (size_t)b * LL + (size_t)ci * CH;

    for (int i = t; i < CH * (DH / 4); i += 256) {
        int r = i >> 6;
        int c4 = (i & 63) * 4;
        ushort4 kv = *(const ushort4*)(k + (qgbase + r) * DD + h * DH + c4);
        kt[r][c4+0] = bf2f(kv.x); kt[r][c4+1] = bf2f(kv.y);
        kt[r][c4+2] = bf2f(kv.z); kt[r][c4+3] = bf2f(kv.w);
    }
    if (t < CH) bet[t] = beta[(qgbase + t) * HH + h];
    __syncthreads();

    int c = t >> 3, e0 = (t & 7) * 4;
    {
        float accA[4] = {0,0,0,0}, accT[4] = {0,0,0,0};
        const unsigned short* qrow = q + (qgbase + c) * DD + h * DH;
        for (int d0 = 0; d0 < DH; d0 += 4) {
            float4 kc = *(const float4*)&kt[c][d0];
            ushort4 qv = *(const ushort4*)(qrow + d0);
            float qx = bf2f(qv.x), qy = bf2f(qv.y), qz = bf2f(qv.z), qw = bf2f(qv.w);
#pragma unroll
            for (int e = 0; e < 4; ++e) {
                float4 ke = *(const float4*)&kt[e0 + e][d0];
                accA[e] += kc.x*ke.x + kc.y*ke.y + kc.z*ke.z + kc.w*ke.w;
                accT[e] += qx*ke.x + qy*ke.y + qz*ke.z + qw*ke.w;
            }
        }
        float bc = bet[c];
        size_t abase = (size_t)blockIdx.x * (CH * CH) + (size_t)c * CH;
#pragma unroll
        for (int e = 0; e < 4; ++e) {
            int ee = e0 + e;
            Am[c][ee] = (ee < c) ? (-bc * accA[e]) : 0.0f;
            attn_out[abase + ee] = (ee <= c) ? accT[e] : 0.0f;
        }
    }
    __syncthreads();

    for (int i = 1; i < CH; ++i) {
        float upd = 0.0f;
        if (t < i) {
#pragma unroll
            for (int kk = 0; kk < CH; ++kk) upd += Am[i][kk] * Am[kk][t];
        }
        __syncthreads();
        if (t < i) Am[i][t] += upd;
        __syncthreads();
    }

    for (int i = t; i < CH * CH; i += 256) {
        int cc = i >> 5, ee = i & 31;
        float val = Am[cc][ee] + (cc == ee ? 1.0f : 0.0f);
        Ab[cc][ee] = val * bet[ee];
    }
    __syncthreads();

    int c2 = t >> 3, dd0 = (t & 7) * 32;
    float accu[32];
#pragma unroll
    for (int j = 0; j < 32; ++j) accu[j] = 0.0f;
    for (int e = 0; e < CH; ++e) {
        float ab = Ab[c2][e];
        const float* vrow = v + (qgbase + e) * DD + h * DH + dd0;
#pragma unroll
        for (int j4 = 0; j4 < 8; ++j4) {
            float4 v4 = *(const float4*)(vrow + j4 * 4);
            accu[j4*4+0] += ab * v4.x; accu[j4*4+1] += ab * v4.y;
            accu[j4*4+2] += ab * v4.z; accu[j4*4+3] += ab * v4.w;
        }
    }
    size_t obase = ((size_t)bh * LL + (size_t)ci * CH + c2) * DH + dd0;
#pragma unroll
    for (int j4 = 0; j4 < 8; ++j4) {
        ushort4 o;
        o.x = f2bf(accu[j4*4+0]); o.y = f2bf(accu[j4*4+1]);
        o.z = f2bf(accu[j4*4+2]); o.w = f2bf(accu[j4*4+3]);
        *(ushort4*)(u_out + obase + j4*4) = o;
    }

#pragma unroll
    for (int j = 0; j < 32; ++j) accu[j] = 0.0f;
    for (int e = 0; e < CH; ++e) {
        float ab = Ab[c2][e];
#pragma unroll
        for (int j4 = 0; j4 < 8; ++j4) {
            float4 v4 = *(const float4*)&kt[e][dd0 + j4*4];
            accu[j4*4+0] += ab * v4.x; accu[j4*4+1] += ab * v4.y;
            accu[j4*4+2] += ab * v4.z; accu[j4*4+3] += ab * v4.w;
        }
    }
#pragma unroll
    for (int j4 = 0; j4 < 8; ++j4) {
        ushort4 o;
        o.x = f2bf(accu[j4*4+0]); o.y = f2bf(accu[j4*4+1]);
        o.z = f2bf(accu[j4*4+2]); o.w = f2bf(accu[j4*4+3]);
        *(ushort4*)(w_out + obase + j4*4) = o;
    }
}

// ------------------------------------------------- chunk scan v2 (R3, verified)
__global__ __launch_bounds__(256) void scan2_k(
    const unsigned short* __restrict__ q, const unsigned short* __restrict__ kT,
    const unsigned short* __restrict__ u, const unsigned short* __restrict__ w,
    const float* __restrict__ attn, float* __restrict__ dout)
{
    const int jb = blockIdx.x & 15;
    const int bh = blockIdx.x >> 4;
    const int h = bh & (HH - 1), b = bh >> 2;
    const int jcol = jb * 16;
    __shared__ float S[DH][20];
    __shared__ float uadj[CH][20];
    const int t = threadIdx.x;
    const int c  = t >> 3;
    const int j0 = (t & 7) * 2;

    for (int i = t; i < DH * 20; i += 256) (&S[0][0])[i] = 0.0f;
    __syncthreads();

    const unsigned short* kTrow = kT + ((size_t)bh * DH + t) * LL;

    for (int ci = 0; ci < NC; ++ci) {
        const size_t rowbase = (size_t)bh * LL + (size_t)ci * CH;
        const size_t qgbase  = (size_t)b  * LL + (size_t)ci * CH;

        ushort2 uv2 = *(const ushort2*)(u + (rowbase + c) * DH + jcol + j0);
        const uint4* ktp = (const uint4*)(kTrow + (size_t)ci * CH);
        uint4 kt0 = ktp[0], kt1 = ktp[1], kt2 = ktp[2], kt3 = ktp[3];

        const uint4* wp = (const uint4*)(w + (rowbase + c) * DH);
        const uint4* qp = (const uint4*)(q + (qgbase + c) * DD + h * DH);
        float t1al=0, t1bl=0, t2al=0, t2bl=0;
        float t1ah=0, t1bh=0, t2ah=0, t2bh=0;
        for (int eb = 0; eb < 32; ++eb) {
            uint4 wv = wp[eb];
            uint4 qv = qp[eb];
            unsigned wu[4] = {wv.x, wv.y, wv.z, wv.w};
            unsigned qu[4] = {qv.x, qv.y, qv.z, qv.w};
            int e0 = eb * 8;
#pragma unroll
            for (int p = 0; p < 4; ++p) {
                int e = e0 + p * 2;
                float2 s0 = *(const float2*)&S[e][j0];
                float2 s1 = *(const float2*)&S[e + 1][j0];
                float wlo = bflo(wu[p]), whi = bfhi(wu[p]);
                float qlo = bflo(qu[p]), qhi = bfhi(qu[p]);
                t1al += wlo * s0.x; t1bl += wlo * s0.y;
                t2al += qlo * s0.x; t2bl += qlo * s0.y;
                t1ah += whi * s1.x; t1bh += whi * s1.y;
                t2ah += qhi * s1.x; t2bh += qhi * s1.y;
            }
        }
        float ua = bf2f(uv2.x) - (t1al + t1ah);
        float ub = bf2f(uv2.y) - (t1bl + t1bh);
        float oa = t2al + t2ah;
        float ob = t2bl + t2bh;
        *(float2*)&uadj[c][j0] = make_float2(ua, ub);
        __syncthreads();

        {
            const float* at = attn + ((size_t)bh * NC + ci) * (CH * CH) + (size_t)c * CH;
#pragma unroll
            for (int q4 = 0; q4 < 8; ++q4) {
                float4 a4 = *(const float4*)(at + q4 * 4);
                int cc = q4 * 4;
                float2 u0 = *(const float2*)&uadj[cc + 0][j0];
                float2 u1 = *(const float2*)&uadj[cc + 1][j0];
                float2 u2 = *(const float2*)&uadj[cc + 2][j0];
                float2 u3 = *(const float2*)&uadj[cc + 3][j0];
                oa += a4.x*u0.x + a4.y*u1.x + a4.z*u2.x + a4.w*u3.x;
                ob += a4.x*u0.y + a4.y*u1.y + a4.z*u2.y + a4.w*u3.y;
            }
            *(float2*)(dout + (rowbase + c) * DH + jcol + j0) = make_float2(oa, ob);
        }

        {
            float4 s0 = *(const float4*)&S[t][0];
            float4 s1 = *(const float4*)&S[t][4];
            float4 s2 = *(const float4*)&S[t][8];
            float4 s3 = *(const float4*)&S[t][12];
            unsigned karr[16] = {kt0.x, kt0.y, kt0.z, kt0.w,
                                 kt1.x, kt1.y, kt1.z, kt1.w,
                                 kt2.x, kt2.y, kt2.z, kt2.w,
                                 kt3.x, kt3.y, kt3.z, kt3.w};
#pragma unroll
            for (int cc = 0; cc < CH; ++cc) {
                unsigned uu = karr[cc >> 1];
                float kv = (cc & 1) ? bfhi(uu) : bflo(uu);
                float4 u0 = *(const float4*)&uadj[cc][0];
                float4 u1 = *(const float4*)&uadj[cc][4];
                float4 u2 = *(const float4*)&uadj[cc][8];
                float4 u3 = *(const float4*)&uadj[cc][12];
                s0.x += kv*u0.x; s0.y += kv*u0.y; s0.z += kv*u0.z; s0.w += kv*u0.w;
                s1.x += kv*u1.x; s1.y += kv*u1.y; s1.z += kv*u1.z; s1.w += kv*u1.w;
                s2.x += kv*u2.x; s2.y += kv*u2.y; s2.z += kv*u2.z; s2.w += kv*u2.w;
                s3.x += kv*u3.x; s3.y += kv*u3.y; s3.z += kv*u3.z; s3.w += kv*u3.w;
            }
            *(float4*)&S[t][0]  = s0;
            *(float4*)&S[t][4]  = s1;
            *(float4*)&S[t][8]  = s2;
            *(float4*)&S[t][12] = s3;
        }
        __syncthreads();
    }
}

// ------------------------------------------------- per-head stats
__global__ __launch_bounds__(256) void stats_k(
    const float* __restrict__ ls, const float* __restrict__ llb,
    const float* __restrict__ dox, const float* __restrict__ v,
    float* __restrict__ stats)
{
    int bl = blockIdx.x;
    int b = bl >> 12, l = bl & (LL - 1);
    int wv = threadIdx.x >> 6, ln = threadIdx.x & 63;
    size_t ibase = (size_t)bl * DD + wv * DH;
    size_t dbase = (((size_t)(b * HH + wv)) * LL + l) * DH;
#pragma unroll
    for (int tn = 0; tn < 4; ++tn) {
        const float* p; size_t base;
        if (tn == 0)      { p = ls;  base = ibase; }
        else if (tn == 1) { p = llb; base = ibase; }
        else if (tn == 2) { p = dox; base = dbase; }
        else              { p = v;   base = ibase; }
        float4 x = *(const float4*)(p + base + ln * 4);
        float sm = x.x + x.y + x.z + x.w;
        float sq = x.x*x.x + x.y*x.y + x.z*x.z + x.w*x.w;
        float sa = fabsf(x.x) + fabsf(x.y) + fabsf(x.z) + fabsf(x.w);
#pragma unroll
        for (int off = 32; off > 0; off >>= 1) {
            sm += __shfl_down(sm, off);
            sq += __shfl_down(sq, off);
            sa += __shfl_down(sa, off);
        }
        if (ln == 0) {
            float mean = sm * (1.0f / DH);
            float var = sq * (1.0f / DH) - mean * mean;
            float am = sa * (1.0f / DH);
            float l2 = sqrtf(sq);
            *(float4*)(stats + (size_t)bl * 64 + wv * 16 + tn * 4) =
                make_float4(mean, var, am, l2);
        }
    }
}

// ------------------------------------------------- gate finish
__global__ __launch_bounds__(256) void gate_fin_k(
    const float* __restrict__ hpart, const float* __restrict__ stats,
    const float* __restrict__ w1, const float* __restrict__ w2,
    const float* __restrict__ b2, const float* __restrict__ ltemp,
    float* __restrict__ fw)
{
    int bl = blockIdx.x;
    int t = threadIdx.x;
    float temp = log1pf(expf(ltemp[0])) + 1e-4f;
    __shared__ float st[HH][16];
    __shared__ float red[4][4];
    if (t < 64) st[t >> 4][t & 15] = stats[(size_t)bl * 64 + t];
    const float* hp = hpart + (size_t)bl * DD;
    __syncthreads();
    for (int h = 0; h < HH; ++h) {
        float lg0=0.f, lg1=0.f, lg2=0.f, lg3=0.f;
#pragma unroll
        for (int ii = 0; ii < 4; ++ii) {
            int e = t * 4 + ii;
            float x = hp[e];
            const float* wr = w1 + (size_t)e * 1040 + 1024;
#pragma unroll
            for (int s = 0; s < 16; ++s) x += st[h][s] * wr[s];
            float g = 0.5f * x * (1.0f + erff(x * 0.70710678118654752f));
            lg0 += g * w2[e];
            lg1 += g * w2[1024 + e];
            lg2 += g * w2[2048 + e];
            lg3 += g * w2[3072 + e];
        }
#pragma unroll
        for (int off = 32; off > 0; off >>= 1) {
            lg0 += __shfl_down(lg0, off); lg1 += __shfl_down(lg1, off);
            lg2 += __shfl_down(lg2, off); lg3 += __shfl_down(lg3, off);
        }
        int wv = t >> 6, ln = t & 63;
        if (ln == 0) { red[wv][0]=lg0; red[wv][1]=lg1; red[wv][2]=lg2; red[wv][3]=lg3; }
        __syncthreads();
        if (t == 0) {
            float l0 = (red[0][0]+red[1][0]+red[2][0]+red[3][0] + b2[0]) / temp;
            float l1 = (red[0][1]+red[1][1]+red[2][1]+red[3][1] + b2[1]) / temp;
            float l2 = (red[0][2]+red[1][2]+red[2][2]+red[3][2] + b2[2]) / temp;
            float l3 = (red[0][3]+red[1][3]+red[2][3]+red[3][3] + b2[3]) / temp;
            float m = fmaxf(fmaxf(l0,l1), fmaxf(l2,l3));
            float e0 = expf(l0-m), e1 = expf(l1-m), e2 = expf(l2-m), e3 = expf(l3-m);
            float inv = 1.0f / (e0+e1+e2+e3);
            *(float4*)(fw + (size_t)bl * 16 + h * 4) =
                make_float4(e0*inv, e1*inv, e2*inv, e3*inv);
        }
        __syncthreads();
    }
}

// ------------------------------------------------- combine + rms norm
__global__ __launch_bounds__(256) void combine_k(
    const float* __restrict__ ls, const float* __restrict__ llb,
    const float* __restrict__ dox, const float* __restrict__ v,
    const float* __restrict__ fw, const float* __restrict__ rss,
    const float* __restrict__ rsl, const float* __restrict__ onw,
    float* __restrict__ opre)
{
    int h = blockIdx.x & (HH - 1);
    int bl = blockIdx.x >> 2;
    int b = bl >> 12, l = bl & (LL - 1);
    int d = threadIdx.x;
    size_t i1 = (size_t)blockIdx.x * DH + d;
    size_t i2 = (((size_t)(b * HH + h)) * LL + l) * DH + d;
    const float* fwp = fw + (size_t)blockIdx.x * 4;
    float f0 = fwp[0], f1 = fwp[1], f2 = fwp[2], f3 = fwp[3];
    float aS = rss[0], aL = rsl[0];
    float vls = ls[i1], vll = llb[i1], vd = dox[i2], vv = v[i1];
    float o = f0*vls + f1*vll + f2*vd + f3*vv + aS*vls + aL*vll;
    float s = o * o;
#pragma unroll
    for (int off = 32; off > 0; off >>= 1) s += __shfl_down(s, off);
    __shared__ float red[4];
    int wv = threadIdx.x >> 6, ln = threadIdx.x & 63;
    if (ln == 0) red[wv] = s;
    __syncthreads();
    float ms = (red[0] + red[1] + red[2] + red[3]) * (1.0f / DH);
    opre[(size_t)bl * DD + h * DH + d] = o * rsqrtf(ms + 1e-5f) * onw[d];
}

// ================================================================ launch
extern "C" void kernel_launch(void* const* d_in, const int* in_sizes, int n_in,
                              void* d_out, int out_size, void* d_ws, size_t ws_size,
                              hipStream_t stream)
{
    const float* hs  = (const float*)d_in[0];
    const float* qw  = (const float*)d_in[1];
    const float* kw  = (const float*)d_in[2];
    const float* vw  = (const float*)d_in[3];
    const float* bw  = (const float*)d_in[4];
    const float* qcw = (const float*)d_in[5];
    const float* kcw = (const float*)d_in[6];
    const float* vcw = (const float*)d_in[7];
    const float* fsw = (const float*)d_in[8];
    const float* flw = (const float*)d_in[9];
    const float* w1  = (const float*)d_in[10];
    const float* b1  = (const float*)d_in[11];
    const float* w2  = (const float*)d_in[12];
    const float* b2  = (const float*)d_in[13];
    const float* lt  = (const float*)d_in[14];
    const float* rss = (const float*)d_in[15];
    const float* rsl = (const float*)d_in[16];
    const float* onw = (const float*)d_in[17];
    const float* opw = (const float*)d_in[18];
    float* out = (float*)d_out;

    float* wsf = (float*)d_ws;
    float* tmp   = wsf;
    float* vbuf  = wsf + BLD;
    float* dbuf  = wsf + 2*BLD;
    unsigned short* qbuf = (unsigned short*)(wsf + 3*BLD);
    unsigned short* kbuf = qbuf + BLD;
    float* hpart = wsf + 3*BLD;
    float* opre  = wsf + 3*BLD;
    unsigned short* ubuf = (unsigned short*)(wsf + 4*BLD);
    unsigned short* wbuf = ubuf + BLD;
    float* llbuf = wsf + 4*BLD;
    float* lsbuf = tmp;
    unsigned short* ktbuf = (unsigned short*)tmp;
    float* attnb = wsf + 5*BLD;
    float* statsb= attnb + (size_t)BB*HH*NC*CH*CH;
    float* fwbuf = statsb + (size_t)BL*HH*16;
    float* betab = fwbuf + (size_t)BL*HH*4;

    dim3 gg(8, 64);   // N/128, M/128

    gemm_mfma<<<gg, 256, 0, stream>>>(hs, DD, qw, DD, nullptr, tmp, DD, DD);
    convnorm_qk_k<<<BL*HH, 256, 0, stream>>>(tmp, qcw, qbuf);
    gemm_mfma<<<gg, 256, 0, stream>>>(hs, DD, kw, DD, nullptr, tmp, DD, DD);
    convnorm_qk_k<<<BL*HH, 256, 0, stream>>>(tmp, kcw, kbuf);
    gemm_mfma<<<gg, 256, 0, stream>>>(hs, DD, vw, DD, nullptr, tmp, DD, DD);
    conv_silu_k<<<(int)(BLD/256), 256, 0, stream>>>(tmp, vcw, vbuf);

    beta_k<<<BL, 256, 0, stream>>>(hs, bw, betab);

    tr_k<<<8*64*4, 256, 0, stream>>>(kbuf, ktbuf);

    chunk_prep_k<<<BB*HH*NC, 256, 0, stream>>>(qbuf, kbuf, vbuf, betab, ubuf, wbuf, attnb);
    scan2_k<<<BB*HH*16, 256, 0, stream>>>(qbuf, ktbuf, ubuf, wbuf, attnb, dbuf);

    fir2_k<5><<<BB*64*16, 256, 0, stream>>>(vbuf, fsw, lsbuf);
    fir2_k<64><<<BB*64*16, 256, 0, stream>>>(vbuf, flw, llbuf);

    stats_k<<<BL, 256, 0, stream>>>(lsbuf, llbuf, dbuf, vbuf, statsb);

    gemm_mfma<<<gg, 256, 0, stream>>>(hs, DD, w1, 1040, b1, hpart, DD, DD);
    gate_fin_k<<<BL, 256, 0, stream>>>(hpart, statsb, w1, w2, b2, lt, fwbuf);

    combine_k<<<BL*HH, 256, 0, stream>>>(lsbuf, llbuf, dbuf, vbuf, fwbuf, rss, rsl, onw, opre);

    gemm_mfma<<<gg, 256, 0, stream>>>(opre, DD, opw, DD, nullptr, out, DD, DD);
}